// Round 18
// baseline (108.673 us; speedup 1.0000x reference)
//
#include <hip/hip_runtime.h>
#include <hip/hip_bf16.h>

typedef unsigned int uint;
typedef unsigned short ushort;
typedef short bf16x8 __attribute__((ext_vector_type(8)));
typedef ushort u16x8 __attribute__((ext_vector_type(8)));
typedef float f32x4 __attribute__((ext_vector_type(4)));

#define B_ 16
#define C_ 256
#define O_ 256
#define HW_ 4096
#define KK_ 2304   // 9 * 256, tap-major: k = tap*256 + c
#define HP_ 66     // halo-padded spatial dim

#define VMW(n) asm volatile("s_waitcnt vmcnt(" #n ")" ::: "memory")
#define LGW(n) asm volatile("s_waitcnt lgkmcnt(" #n ")" ::: "memory")
#define SB0 __builtin_amdgcn_sched_barrier(0)
#define PRIO1 __builtin_amdgcn_s_setprio(1)
#define PRIO0 __builtin_amdgcn_s_setprio(0)
#define BAR __builtin_amdgcn_s_barrier()

__device__ __forceinline__ ushort f2bf(float f) {
    uint u = __builtin_bit_cast(uint, f);
    uint r = (u + 0x7FFFu + ((u >> 16) & 1u)) >> 16;   // RNE
    return (ushort)r;
}

// async global->LDS, 16B per lane; LDS dest is wave-uniform base + lane*16
__device__ __forceinline__ void gl16(const ushort* g, ushort* l) {
    __builtin_amdgcn_global_load_lds(
        (const __attribute__((address_space(1))) void*)g,
        (__attribute__((address_space(3))) void*)l,
        16, 0, 0);
}

// ---------------- kernel 1: NCHW f32 -> padded NHWC bf16 + pool partials + halo ------
__global__ __launch_bounds__(256) void transpose_kernel(const float* __restrict__ x,
                                                        ushort* __restrict__ xT,
                                                        float* __restrict__ part) {
    __shared__ ushort tl[64][264];   // [w][c], pad 8 -> row stride 528B
    const int h = blockIdx.x, b = blockIdx.y;
    const int c = threadIdx.x;
    const float* src = x + (((size_t)(b * C_ + c)) * 64 + h) * 64;   // x[b][c][h][*]
    float s = 0.0f;
    #pragma unroll
    for (int j = 0; j < 16; ++j) {
        float4 v = ((const float4*)src)[j];
        s += v.x + v.y + v.z + v.w;
        tl[j * 4 + 0][c] = f2bf(v.x);
        tl[j * 4 + 1][c] = f2bf(v.y);
        tl[j * 4 + 2][c] = f2bf(v.z);
        tl[j * 4 + 3][c] = f2bf(v.w);
    }
    part[(b * C_ + c) * 64 + h] = s;
    // zero 5 halo pixels per block (260 total per sample, 64 blocks x 5 = 320 >= 260)
    ushort* xbs = xT + (size_t)b * HP_ * HP_ * C_;
    #pragma unroll
    for (int t = 0; t < 5; ++t) {
        int i = h * 5 + t;
        if (i < 260) {
            int hp, wp;
            if (i < 66)       { hp = 0;       wp = i;       }
            else if (i < 132) { hp = 65;      wp = i - 66;  }
            else if (i < 196) { hp = i - 131; wp = 0;       }
            else              { hp = i - 195; wp = 65;      }
            xbs[((size_t)hp * HP_ + wp) * C_ + c] = 0;
        }
    }
    __syncthreads();
    const int cw = threadIdx.x & 31, rw = threadIdx.x >> 5;
    ushort* dstrow = xT + (((size_t)(b * HP_) + h + 1) * HP_ + 1) * C_;  // xT[b][h+1][1][0]
    #pragma unroll
    for (int j = 0; j < 8; ++j) {
        int w = rw + 8 * j;
        *(u16x8*)(dstrow + (size_t)w * C_ + cw * 8) = *(const u16x8*)&tl[w][cw * 8];
    }
}

// ---------------- kernel 2: pooled reduce + gating softmax ----------------
__global__ __launch_bounds__(256) void gate_kernel(const float* __restrict__ part,
                                                   const float* __restrict__ gw,
                                                   float* __restrict__ gates) {
    const int b = blockIdx.x, c = threadIdx.x;
    const float4* pp = (const float4*)(part + (size_t)(b * C_ + c) * 64);
    float p = 0.0f;
    #pragma unroll
    for (int j = 0; j < 16; ++j) { float4 v = pp[j]; p += v.x + v.y + v.z + v.w; }
    p *= (1.0f / 4096.0f);
    float l0 = p * gw[0 * C_ + c], l1 = p * gw[1 * C_ + c];
    float l2 = p * gw[2 * C_ + c], l3 = p * gw[3 * C_ + c];
    #pragma unroll
    for (int off = 32; off; off >>= 1) {
        l0 += __shfl_down(l0, off); l1 += __shfl_down(l1, off);
        l2 += __shfl_down(l2, off); l3 += __shfl_down(l3, off);
    }
    __shared__ float red[4][4];
    const int wid = c >> 6, lane = c & 63;
    if (lane == 0) { red[wid][0] = l0; red[wid][1] = l1; red[wid][2] = l2; red[wid][3] = l3; }
    __syncthreads();
    if (c < 4) {
        float logit = red[0][c] + red[1][c] + red[2][c] + red[3][c];
        float m = logit;
        m = fmaxf(m, __shfl_xor(m, 1)); m = fmaxf(m, __shfl_xor(m, 2));
        float ex = expf(logit - m);
        float ssum = ex; ssum += __shfl_xor(ssum, 1); ssum += __shfl_xor(ssum, 2);
        gates[b * 4 + c] = ex / ssum;
    }
}

// ---------------- kernel 3: combine expert weights (tap-major k) ----------------
__global__ __launch_bounds__(256) void combine_kernel(const float* __restrict__ We,
                                                      const float* __restrict__ gates,
                                                      ushort* __restrict__ Wc) {
    const int o = blockIdx.x, c = threadIdx.x;
    __shared__ float g[64];
    if (c < 64) g[c] = gates[c];
    __syncthreads();
    float w[4][9];
    #pragma unroll
    for (int e = 0; e < 4; ++e) {
        const float* p = We + (((size_t)e * O_ + o) * C_ + c) * 9;
        #pragma unroll
        for (int tap = 0; tap < 9; ++tap) w[e][tap] = p[tap];
    }
    #pragma unroll
    for (int b = 0; b < B_; ++b) {
        float g0 = g[b*4+0], g1 = g[b*4+1], g2 = g[b*4+2], g3 = g[b*4+3];
        #pragma unroll
        for (int tap = 0; tap < 9; ++tap) {
            float v = g0*w[0][tap] + g1*w[1][tap] + g2*w[2][tap] + g3*w[3][tap];
            Wc[((size_t)(b * O_ + o)) * KK_ + tap * C_ + c] = f2bf(v);
        }
    }
}

// ---------------- kernel 4: 256x256 conv GEMM — R15 skeleton, P1+P2 merged ----------
// grid = 256 blocks = 1/CU, 512 threads (8 waves, 2M x 4N; wave 128x64). 36 K-tiles
// of BK=64, 2 dbuf (128KB), R7's 0-conflict 128B-row XOR swizzle.
// R15's 4-phase double-barrier schedule with phases P1,P2 merged via a mid-phase
// LGW(0) (no hazard between them: reads from dd only, stage rows disjoint) ->
// 6 barriers/tile instead of 8. Everything else identical to R15 (79us verified):
// same-phase reads, stage order A0|A1,B0|B1, counted VMW(2) at P0/P3 (never 0
// mid-loop), every cross-wave DMA->read pair separated by a VMW-then-BAR.
__global__ __launch_bounds__(512, 2) void conv_kernel(const ushort* __restrict__ xT,
                                                      const ushort* __restrict__ Wc,
                                                      float* __restrict__ out) {
    __shared__ ushort As[2][256][64];   // [dbuf][o][k]  128B rows, linear DMA dest
    __shared__ ushort Bs[2][256][64];   // [dbuf][px][k]

    // bijective XCD chunk swizzle: 32 consecutive wgids per XCD (2 samples/XCD)
    const int d0 = blockIdx.x;
    const int wgid = (d0 & 7) * 32 + (d0 >> 3);
    const int b  = wgid >> 4;
    const int n0 = (wgid & 15) * 256;

    const int tid = threadIdx.x;
    const int wid = tid >> 6, lane = tid & 63;
    const int lr = lane & 15, lg = lane >> 4;
    const int wro = (wid >> 2) * 128;           // wave M-offset (o)
    const int wco = (wid & 3) * 64;             // wave N-offset (px)

    // staging lane roles (R7 swizzle: row = lane>>3, granule = (lane&7)^row)
    const int srow = lane >> 3;                 // 0..7
    const int sgr  = (lane & 7) ^ srow;
    const int rA = (wid >> 2) * 128 + (wid & 3) * 16;
    const ushort* aSb = Wc + ((size_t)(b * O_ + rA + srow)) * KK_ + sgr * 8;
    const ushort* xb = xT + (size_t)b * HP_ * HP_ * C_;
    const int hh  = (n0 >> 6) + (wid & 3);      // image row staged by this wave (uniform)
    const int pW  = (wid >> 2) * 16;            // px offset within row-half
    const ushort* bSb = xb + ((size_t)(hh + 1) * HP_ + pW + srow + 1) * C_ + sgr * 8;

    f32x4 acc[8][4];
    #pragma unroll
    for (int i = 0; i < 8; ++i)
        #pragma unroll
        for (int j = 0; j < 4; ++j) acc[i][j] = (f32x4){0.f, 0.f, 0.f, 0.f};

    auto stageA = [&](int dn, int t, int ah) {
        #pragma unroll
        for (int i = 0; i < 2; ++i)
            gl16(aSb + (size_t)(ah * 64 + i * 8) * KK_ + t * 64,
                 &As[dn][rA + ah * 64 + i * 8][0]);
    };
    auto stageB = [&](int dn, int t, int bh) {
        const int tap = t >> 2, c0 = (t & 3) * 64;
        const int t3 = (tap * 11) >> 5;          // tap/3
        const int toff = ((t3 - 1) * HP_ + (tap - 3 * t3 - 1)) * C_ + c0;
        #pragma unroll
        for (int i = 0; i < 2; ++i)
            gl16(bSb + (size_t)(bh * 32 + i * 8) * C_ + toff,
                 &Bs[dn][wco + pW + bh * 32 + i * 8][0]);
    };

    bf16x8 aF[4][2], bF0[2][2], bF1[2][2];

    auto rdA = [&](int dd, int mh, bf16x8 dst[4][2]) {
        #pragma unroll
        for (int m = 0; m < 4; ++m)
            #pragma unroll
            for (int k = 0; k < 2; ++k)
                dst[m][k] = *(const bf16x8*)
                    &As[dd][wro + mh * 64 + m * 16 + lr][(((k << 2) | lg) ^ (lr & 7)) * 8];
    };
    auto rdB = [&](int dd, int nh, bf16x8 dst[2][2]) {
        #pragma unroll
        for (int n = 0; n < 2; ++n)
            #pragma unroll
            for (int k = 0; k < 2; ++k)
                dst[n][k] = *(const bf16x8*)
                    &Bs[dd][wco + nh * 32 + n * 16 + lr][(((k << 2) | lg) ^ (lr & 7)) * 8];
    };
    auto mfmaQ = [&](int m0, int n0q, bf16x8 a[4][2], bf16x8 bv[2][2]) {
        #pragma unroll
        for (int m = 0; m < 4; ++m)
            #pragma unroll
            for (int n = 0; n < 2; ++n)
                #pragma unroll
                for (int k = 0; k < 2; ++k)
                    acc[m0 + m][n0q + n] =
                        __builtin_amdgcn_mfma_f32_16x16x32_bf16(a[m][k], bv[n][k], acc[m0 + m][n0q + n], 0, 0, 0);
    };

    // prologue: stage tile 0 fully into dbuf 0 (order A0,A1,B0,B1); VMW(2)+BAR
    stageA(0, 0, 0); stageA(0, 0, 1); stageB(0, 0, 0); stageB(0, 0, 1);
    VMW(2);                    // A0,A1,B0 landed; B1 (last pair) still in flight
    BAR;

    #pragma unroll 1
    for (int t = 0; t < 35; ++t) {
        const int dd = t & 1, dn = dd ^ 1;
        // P0: reads A(mh0)+B(nh0); stage A-half0(t+1); VMW(2) drains prev B1 at end
        rdA(dd, 0, aF); rdB(dd, 0, bF0);
        stageA(dn, t + 1, 0);
        BAR;
        LGW(0); SB0;
        PRIO1; mfmaQ(0, 0, aF, bF0); PRIO0;
        VMW(2);                // prev tile's B1 landed; own A-half0 in flight
        BAR;
        // P1+P2 merged: reads B(nh1); stage A-half1(t+1); MFMA; then re-read A(mh1),
        // stage B-half0(t+1), mid-phase LGW(0), MFMA. No hazard: all reads from dd,
        // all stages into dn disjoint rows. Saves 2 barriers vs R15.
        rdB(dd, 1, bF1);
        stageA(dn, t + 1, 1);
        BAR;
        LGW(0); SB0;
        PRIO1; mfmaQ(0, 2, aF, bF1); PRIO0;
        rdA(dd, 1, aF);        // overwrites aF after its h0 use (program order, no WAR)
        stageB(dn, t + 1, 0);
        LGW(0); SB0;
        PRIO1; mfmaQ(4, 2, aF, bF1); PRIO0;
        BAR;
        // P3: no reads; stage B-half1(t+1); VMW(2) leaves only B1(t+1) in flight
        stageB(dn, t + 1, 1);
        BAR;
        PRIO1; mfmaQ(4, 0, aF, bF0); PRIO0;
        VMW(2);                // A0',A1',B0' of t+1 landed; B1' in flight
        BAR;
    }
    // tile 35 (dbuf 1), no staging
    {
        rdA(1, 0, aF); rdB(1, 0, bF0);
        BAR;
        LGW(0); SB0;
        PRIO1; mfmaQ(0, 0, aF, bF0); PRIO0;
        VMW(0);                // drain tile-34's B1
        BAR;
        rdB(1, 1, bF1);
        BAR;
        LGW(0); SB0;
        PRIO1; mfmaQ(0, 2, aF, bF1); PRIO0;
        rdA(1, 1, aF);
        LGW(0); SB0;
        PRIO1; mfmaQ(4, 2, aF, bF1); PRIO0;
        BAR;
        PRIO1; mfmaQ(4, 0, aF, bF0); PRIO0;
    }

    // epilogue: C/D layout col=lane&15, row=(lane>>4)*4+j
    #pragma unroll
    for (int m = 0; m < 8; ++m)
        #pragma unroll
        for (int n = 0; n < 4; ++n)
            #pragma unroll
            for (int j = 0; j < 4; ++j) {
                int ro = wro + m * 16 + lg * 4 + j;
                int co = n0 + wco + n * 16 + lr;
                out[((size_t)(b * O_ + ro)) * HW_ + co] = acc[m][n][j];
            }
}

extern "C" void kernel_launch(void* const* d_in, const int* in_sizes, int n_in,
                              void* d_out, int out_size, void* d_ws, size_t ws_size,
                              hipStream_t stream) {
    const float* x  = (const float*)d_in[0];
    const float* We = (const float*)d_in[1];
    const float* gw = (const float*)d_in[2];
    float* out = (float*)d_out;

    // ws: part @0 (256KB), gates @262144, Wc @263168 (18.87MB -> 19137536),
    //     xT @19137536 (16*66*66*256*2B = 35.68MB) -> ~54.8MB total
    float*  part  = (float*)d_ws;
    float*  gates = (float*)((char*)d_ws + 262144);
    ushort* Wcomb = (ushort*)((char*)d_ws + 263168);
    ushort* xTp   = (ushort*)((char*)d_ws + 19137536);

    transpose_kernel<<<dim3(64, 16), 256, 0, stream>>>(x, xTp, part);
    gate_kernel<<<16, 256, 0, stream>>>(part, gw, gates);
    combine_kernel<<<O_, 256, 0, stream>>>(We, gates, Wcomb);
    conv_kernel<<<256, 512, 0, stream>>>(xTp, Wcomb, out);
}

// Round 19
// 105.901 us; speedup vs baseline: 1.0262x; 1.0262x over previous
//
#include <hip/hip_runtime.h>
#include <hip/hip_bf16.h>

typedef unsigned int uint;
typedef unsigned short ushort;
typedef short bf16x8 __attribute__((ext_vector_type(8)));
typedef ushort u16x8 __attribute__((ext_vector_type(8)));
typedef float f32x4 __attribute__((ext_vector_type(4)));

#define B_ 16
#define C_ 256
#define O_ 256
#define HW_ 4096
#define KK_ 2304   // 9 * 256, tap-major: k = tap*256 + c
#define HP_ 66     // halo-padded spatial dim

#define VMW(n) asm volatile("s_waitcnt vmcnt(" #n ")" ::: "memory")
#define LGW(n) asm volatile("s_waitcnt lgkmcnt(" #n ")" ::: "memory")
#define SB0 __builtin_amdgcn_sched_barrier(0)
#define PRIO1 __builtin_amdgcn_s_setprio(1)
#define PRIO0 __builtin_amdgcn_s_setprio(0)
#define BAR __builtin_amdgcn_s_barrier()

__device__ __forceinline__ ushort f2bf(float f) {
    uint u = __builtin_bit_cast(uint, f);
    uint r = (u + 0x7FFFu + ((u >> 16) & 1u)) >> 16;   // RNE
    return (ushort)r;
}

// async global->LDS, 16B per lane; LDS dest is wave-uniform base + lane*16
__device__ __forceinline__ void gl16(const ushort* g, ushort* l) {
    __builtin_amdgcn_global_load_lds(
        (const __attribute__((address_space(1))) void*)g,
        (__attribute__((address_space(3))) void*)l,
        16, 0, 0);
}

// ---------------- kernel 1: NCHW f32 -> padded NHWC bf16 + pool partials + halo ------
__global__ __launch_bounds__(256) void transpose_kernel(const float* __restrict__ x,
                                                        ushort* __restrict__ xT,
                                                        float* __restrict__ part) {
    __shared__ ushort tl[64][264];   // [w][c], pad 8 -> row stride 528B
    const int h = blockIdx.x, b = blockIdx.y;
    const int c = threadIdx.x;
    const float* src = x + (((size_t)(b * C_ + c)) * 64 + h) * 64;   // x[b][c][h][*]
    float s = 0.0f;
    #pragma unroll
    for (int j = 0; j < 16; ++j) {
        float4 v = ((const float4*)src)[j];
        s += v.x + v.y + v.z + v.w;
        tl[j * 4 + 0][c] = f2bf(v.x);
        tl[j * 4 + 1][c] = f2bf(v.y);
        tl[j * 4 + 2][c] = f2bf(v.z);
        tl[j * 4 + 3][c] = f2bf(v.w);
    }
    part[(b * C_ + c) * 64 + h] = s;
    // zero 5 halo pixels per block (260 total per sample, 64 blocks x 5 = 320 >= 260)
    ushort* xbs = xT + (size_t)b * HP_ * HP_ * C_;
    #pragma unroll
    for (int t = 0; t < 5; ++t) {
        int i = h * 5 + t;
        if (i < 260) {
            int hp, wp;
            if (i < 66)       { hp = 0;       wp = i;       }
            else if (i < 132) { hp = 65;      wp = i - 66;  }
            else if (i < 196) { hp = i - 131; wp = 0;       }
            else              { hp = i - 195; wp = 65;      }
            xbs[((size_t)hp * HP_ + wp) * C_ + c] = 0;
        }
    }
    __syncthreads();
    const int cw = threadIdx.x & 31, rw = threadIdx.x >> 5;
    ushort* dstrow = xT + (((size_t)(b * HP_) + h + 1) * HP_ + 1) * C_;  // xT[b][h+1][1][0]
    #pragma unroll
    for (int j = 0; j < 8; ++j) {
        int w = rw + 8 * j;
        *(u16x8*)(dstrow + (size_t)w * C_ + cw * 8) = *(const u16x8*)&tl[w][cw * 8];
    }
}

// ---------------- kernel 2: pooled reduce + gating softmax ----------------
__global__ __launch_bounds__(256) void gate_kernel(const float* __restrict__ part,
                                                   const float* __restrict__ gw,
                                                   float* __restrict__ gates) {
    const int b = blockIdx.x, c = threadIdx.x;
    const float4* pp = (const float4*)(part + (size_t)(b * C_ + c) * 64);
    float p = 0.0f;
    #pragma unroll
    for (int j = 0; j < 16; ++j) { float4 v = pp[j]; p += v.x + v.y + v.z + v.w; }
    p *= (1.0f / 4096.0f);
    float l0 = p * gw[0 * C_ + c], l1 = p * gw[1 * C_ + c];
    float l2 = p * gw[2 * C_ + c], l3 = p * gw[3 * C_ + c];
    #pragma unroll
    for (int off = 32; off; off >>= 1) {
        l0 += __shfl_down(l0, off); l1 += __shfl_down(l1, off);
        l2 += __shfl_down(l2, off); l3 += __shfl_down(l3, off);
    }
    __shared__ float red[4][4];
    const int wid = c >> 6, lane = c & 63;
    if (lane == 0) { red[wid][0] = l0; red[wid][1] = l1; red[wid][2] = l2; red[wid][3] = l3; }
    __syncthreads();
    if (c < 4) {
        float logit = red[0][c] + red[1][c] + red[2][c] + red[3][c];
        float m = logit;
        m = fmaxf(m, __shfl_xor(m, 1)); m = fmaxf(m, __shfl_xor(m, 2));
        float ex = expf(logit - m);
        float ssum = ex; ssum += __shfl_xor(ssum, 1); ssum += __shfl_xor(ssum, 2);
        gates[b * 4 + c] = ex / ssum;
    }
}

// ---------------- kernel 3: combine expert weights (tap-major k) ----------------
__global__ __launch_bounds__(256) void combine_kernel(const float* __restrict__ We,
                                                      const float* __restrict__ gates,
                                                      ushort* __restrict__ Wc) {
    const int o = blockIdx.x, c = threadIdx.x;
    __shared__ float g[64];
    if (c < 64) g[c] = gates[c];
    __syncthreads();
    float w[4][9];
    #pragma unroll
    for (int e = 0; e < 4; ++e) {
        const float* p = We + (((size_t)e * O_ + o) * C_ + c) * 9;
        #pragma unroll
        for (int tap = 0; tap < 9; ++tap) w[e][tap] = p[tap];
    }
    #pragma unroll
    for (int b = 0; b < B_; ++b) {
        float g0 = g[b*4+0], g1 = g[b*4+1], g2 = g[b*4+2], g3 = g[b*4+3];
        #pragma unroll
        for (int tap = 0; tap < 9; ++tap) {
            float v = g0*w[0][tap] + g1*w[1][tap] + g2*w[2][tap] + g3*w[3][tap];
            Wc[((size_t)(b * O_ + o)) * KK_ + tap * C_ + c] = f2bf(v);
        }
    }
}

// ---------------- kernel 4: 256x256 conv GEMM — R18 skeleton, P12+P3 merged ---------
// grid = 256 blocks = 1/CU, 512 threads (8 waves, 2M x 4N; wave 128x64). 36 K-tiles
// of BK=64, 2 dbuf (128KB), R7's 0-conflict 128B-row XOR swizzle.
// 2 phases/tile, 4 barriers/tile (was 6 in R18, 8 in R15). Hazard invariants kept:
// (1) next-tile stage into dd follows BAR4, by which every wave's dd-reads drained
//     (mid-phase LGW(0) precedes BAR4);
// (2) reads of dn A0/B0 follow BAR4 with VMW(2) leaving only B1 in flight; the B1
//     read next tile follows that tile's P0 VMW(2)+BAR which drains it.
// vm-FIFO stage order A0 | A1,B0,B1 and both VMW(2) counts unchanged (never 0).
__global__ __launch_bounds__(512, 2) void conv_kernel(const ushort* __restrict__ xT,
                                                      const ushort* __restrict__ Wc,
                                                      float* __restrict__ out) {
    __shared__ ushort As[2][256][64];   // [dbuf][o][k]  128B rows, linear DMA dest
    __shared__ ushort Bs[2][256][64];   // [dbuf][px][k]

    // bijective XCD chunk swizzle: 32 consecutive wgids per XCD (2 samples/XCD)
    const int d0 = blockIdx.x;
    const int wgid = (d0 & 7) * 32 + (d0 >> 3);
    const int b  = wgid >> 4;
    const int n0 = (wgid & 15) * 256;

    const int tid = threadIdx.x;
    const int wid = tid >> 6, lane = tid & 63;
    const int lr = lane & 15, lg = lane >> 4;
    const int wro = (wid >> 2) * 128;           // wave M-offset (o)
    const int wco = (wid & 3) * 64;             // wave N-offset (px)

    // staging lane roles (R7 swizzle: row = lane>>3, granule = (lane&7)^row)
    const int srow = lane >> 3;                 // 0..7
    const int sgr  = (lane & 7) ^ srow;
    const int rA = (wid >> 2) * 128 + (wid & 3) * 16;
    const ushort* aSb = Wc + ((size_t)(b * O_ + rA + srow)) * KK_ + sgr * 8;
    const ushort* xb = xT + (size_t)b * HP_ * HP_ * C_;
    const int hh  = (n0 >> 6) + (wid & 3);      // image row staged by this wave (uniform)
    const int pW  = (wid >> 2) * 16;            // px offset within row-half
    const ushort* bSb = xb + ((size_t)(hh + 1) * HP_ + pW + srow + 1) * C_ + sgr * 8;

    f32x4 acc[8][4];
    #pragma unroll
    for (int i = 0; i < 8; ++i)
        #pragma unroll
        for (int j = 0; j < 4; ++j) acc[i][j] = (f32x4){0.f, 0.f, 0.f, 0.f};

    auto stageA = [&](int dn, int t, int ah) {
        #pragma unroll
        for (int i = 0; i < 2; ++i)
            gl16(aSb + (size_t)(ah * 64 + i * 8) * KK_ + t * 64,
                 &As[dn][rA + ah * 64 + i * 8][0]);
    };
    auto stageB = [&](int dn, int t, int bh) {
        const int tap = t >> 2, c0 = (t & 3) * 64;
        const int t3 = (tap * 11) >> 5;          // tap/3
        const int toff = ((t3 - 1) * HP_ + (tap - 3 * t3 - 1)) * C_ + c0;
        #pragma unroll
        for (int i = 0; i < 2; ++i)
            gl16(bSb + (size_t)(bh * 32 + i * 8) * C_ + toff,
                 &Bs[dn][wco + pW + bh * 32 + i * 8][0]);
    };

    bf16x8 aF[4][2], bF0[2][2], bF1[2][2];

    auto rdA = [&](int dd, int mh, bf16x8 dst[4][2]) {
        #pragma unroll
        for (int m = 0; m < 4; ++m)
            #pragma unroll
            for (int k = 0; k < 2; ++k)
                dst[m][k] = *(const bf16x8*)
                    &As[dd][wro + mh * 64 + m * 16 + lr][(((k << 2) | lg) ^ (lr & 7)) * 8];
    };
    auto rdB = [&](int dd, int nh, bf16x8 dst[2][2]) {
        #pragma unroll
        for (int n = 0; n < 2; ++n)
            #pragma unroll
            for (int k = 0; k < 2; ++k)
                dst[n][k] = *(const bf16x8*)
                    &Bs[dd][wco + nh * 32 + n * 16 + lr][(((k << 2) | lg) ^ (lr & 7)) * 8];
    };
    auto mfmaQ = [&](int m0, int n0q, bf16x8 a[4][2], bf16x8 bv[2][2]) {
        #pragma unroll
        for (int m = 0; m < 4; ++m)
            #pragma unroll
            for (int n = 0; n < 2; ++n)
                #pragma unroll
                for (int k = 0; k < 2; ++k)
                    acc[m0 + m][n0q + n] =
                        __builtin_amdgcn_mfma_f32_16x16x32_bf16(a[m][k], bv[n][k], acc[m0 + m][n0q + n], 0, 0, 0);
    };

    // prologue: stage tile 0 fully into dbuf 0 (order A0,A1,B0,B1); VMW(2)+BAR
    stageA(0, 0, 0); stageA(0, 0, 1); stageB(0, 0, 0); stageB(0, 0, 1);
    VMW(2);                    // A0,A1,B0 landed; B1 (last pair) still in flight
    BAR;

    #pragma unroll 1
    for (int t = 0; t < 35; ++t) {
        const int dd = t & 1, dn = dd ^ 1;
        // P0: reads A(mh0)+B(nh0); stage A-half0(t+1); VMW(2) drains prev B1
        rdA(dd, 0, aF); rdB(dd, 0, bF0);
        stageA(dn, t + 1, 0);
        BAR;                   // BAR1
        LGW(0); SB0;
        PRIO1; mfmaQ(0, 0, aF, bF0); PRIO0;
        VMW(2);                // prev tile's B1 landed; own A-half0 in flight
        BAR;                   // BAR2
        // P123 merged: rdB1+stageA1 | MFMA | rdA-h1+stageB0 | MFMA | stageB1+MFMA
        rdB(dd, 1, bF1);
        stageA(dn, t + 1, 1);
        BAR;                   // BAR3
        LGW(0); SB0;
        PRIO1; mfmaQ(0, 2, aF, bF1); PRIO0;
        rdA(dd, 1, aF);        // overwrites aF after its h0 use (program order, no WAR)
        stageB(dn, t + 1, 0);
        LGW(0); SB0;
        PRIO1; mfmaQ(4, 2, aF, bF1); PRIO0;
        stageB(dn, t + 1, 1);
        PRIO1; mfmaQ(4, 0, aF, bF0); PRIO0;
        VMW(2);                // A0',A1',B0' of t+1 landed; B1' in flight
        BAR;                   // BAR4
    }
    // tile 35 (dbuf 1), no staging
    {
        rdA(1, 0, aF); rdB(1, 0, bF0);
        BAR;
        LGW(0); SB0;
        PRIO1; mfmaQ(0, 0, aF, bF0); PRIO0;
        VMW(0);                // drain tile-34's B1
        BAR;
        rdB(1, 1, bF1);
        BAR;
        LGW(0); SB0;
        PRIO1; mfmaQ(0, 2, aF, bF1); PRIO0;
        rdA(1, 1, aF);
        LGW(0); SB0;
        PRIO1; mfmaQ(4, 2, aF, bF1); PRIO0;
        PRIO1; mfmaQ(4, 0, aF, bF0); PRIO0;
    }

    // epilogue: C/D layout col=lane&15, row=(lane>>4)*4+j
    #pragma unroll
    for (int m = 0; m < 8; ++m)
        #pragma unroll
        for (int n = 0; n < 4; ++n)
            #pragma unroll
            for (int j = 0; j < 4; ++j) {
                int ro = wro + m * 16 + lg * 4 + j;
                int co = n0 + wco + n * 16 + lr;
                out[((size_t)(b * O_ + ro)) * HW_ + co] = acc[m][n][j];
            }
}

extern "C" void kernel_launch(void* const* d_in, const int* in_sizes, int n_in,
                              void* d_out, int out_size, void* d_ws, size_t ws_size,
                              hipStream_t stream) {
    const float* x  = (const float*)d_in[0];
    const float* We = (const float*)d_in[1];
    const float* gw = (const float*)d_in[2];
    float* out = (float*)d_out;

    // ws: part @0 (256KB), gates @262144, Wc @263168 (18.87MB -> 19137536),
    //     xT @19137536 (16*66*66*256*2B = 35.68MB) -> ~54.8MB total
    float*  part  = (float*)d_ws;
    float*  gates = (float*)((char*)d_ws + 262144);
    ushort* Wcomb = (ushort*)((char*)d_ws + 263168);
    ushort* xTp   = (ushort*)((char*)d_ws + 19137536);

    transpose_kernel<<<dim3(64, 16), 256, 0, stream>>>(x, xTp, part);
    gate_kernel<<<16, 256, 0, stream>>>(part, gw, gates);
    combine_kernel<<<O_, 256, 0, stream>>>(We, gates, Wcomb);
    conv_kernel<<<256, 512, 0, stream>>>(xTp, Wcomb, out);
}

// Round 20
// 105.641 us; speedup vs baseline: 1.0287x; 1.0025x over previous
//
#include <hip/hip_runtime.h>
#include <hip/hip_bf16.h>

typedef unsigned int uint;
typedef unsigned short ushort;
typedef short bf16x8 __attribute__((ext_vector_type(8)));
typedef ushort u16x8 __attribute__((ext_vector_type(8)));
typedef float f32x4 __attribute__((ext_vector_type(4)));

#define B_ 16
#define C_ 256
#define O_ 256
#define HW_ 4096
#define KK_ 2304   // 9 * 256, tap-major: k = tap*256 + c
#define HP_ 66     // halo-padded spatial dim

#define VMW(n) asm volatile("s_waitcnt vmcnt(" #n ")" ::: "memory")
#define LGW(n) asm volatile("s_waitcnt lgkmcnt(" #n ")" ::: "memory")
#define SB0 __builtin_amdgcn_sched_barrier(0)
#define PRIO1 __builtin_amdgcn_s_setprio(1)
#define PRIO0 __builtin_amdgcn_s_setprio(0)
#define BAR __builtin_amdgcn_s_barrier()

__device__ __forceinline__ ushort f2bf(float f) {
    uint u = __builtin_bit_cast(uint, f);
    uint r = (u + 0x7FFFu + ((u >> 16) & 1u)) >> 16;   // RNE
    return (ushort)r;
}

// async global->LDS, 16B per lane; LDS dest is wave-uniform base + lane*16
__device__ __forceinline__ void gl16(const ushort* g, ushort* l) {
    __builtin_amdgcn_global_load_lds(
        (const __attribute__((address_space(1))) void*)g,
        (__attribute__((address_space(3))) void*)l,
        16, 0, 0);
}

// ---------------- kernel 1: NCHW f32 -> padded NHWC bf16 + pool partials + halo ------
__global__ __launch_bounds__(256) void transpose_kernel(const float* __restrict__ x,
                                                        ushort* __restrict__ xT,
                                                        float* __restrict__ part) {
    __shared__ ushort tl[64][264];   // [w][c], pad 8 -> row stride 528B
    const int h = blockIdx.x, b = blockIdx.y;
    const int c = threadIdx.x;
    const float* src = x + (((size_t)(b * C_ + c)) * 64 + h) * 64;   // x[b][c][h][*]
    float s = 0.0f;
    #pragma unroll
    for (int j = 0; j < 16; ++j) {
        float4 v = ((const float4*)src)[j];
        s += v.x + v.y + v.z + v.w;
        tl[j * 4 + 0][c] = f2bf(v.x);
        tl[j * 4 + 1][c] = f2bf(v.y);
        tl[j * 4 + 2][c] = f2bf(v.z);
        tl[j * 4 + 3][c] = f2bf(v.w);
    }
    part[(b * C_ + c) * 64 + h] = s;
    // zero 5 halo pixels per block (260 total per sample, 64 blocks x 5 = 320 >= 260)
    ushort* xbs = xT + (size_t)b * HP_ * HP_ * C_;
    #pragma unroll
    for (int t = 0; t < 5; ++t) {
        int i = h * 5 + t;
        if (i < 260) {
            int hp, wp;
            if (i < 66)       { hp = 0;       wp = i;       }
            else if (i < 132) { hp = 65;      wp = i - 66;  }
            else if (i < 196) { hp = i - 131; wp = 0;       }
            else              { hp = i - 195; wp = 65;      }
            xbs[((size_t)hp * HP_ + wp) * C_ + c] = 0;
        }
    }
    __syncthreads();
    const int cw = threadIdx.x & 31, rw = threadIdx.x >> 5;
    ushort* dstrow = xT + (((size_t)(b * HP_) + h + 1) * HP_ + 1) * C_;  // xT[b][h+1][1][0]
    #pragma unroll
    for (int j = 0; j < 8; ++j) {
        int w = rw + 8 * j;
        *(u16x8*)(dstrow + (size_t)w * C_ + cw * 8) = *(const u16x8*)&tl[w][cw * 8];
    }
}

// ---------------- kernel 2: pooled reduce + gating softmax ----------------
__global__ __launch_bounds__(256) void gate_kernel(const float* __restrict__ part,
                                                   const float* __restrict__ gw,
                                                   float* __restrict__ gates) {
    const int b = blockIdx.x, c = threadIdx.x;
    const float4* pp = (const float4*)(part + (size_t)(b * C_ + c) * 64);
    float p = 0.0f;
    #pragma unroll
    for (int j = 0; j < 16; ++j) { float4 v = pp[j]; p += v.x + v.y + v.z + v.w; }
    p *= (1.0f / 4096.0f);
    float l0 = p * gw[0 * C_ + c], l1 = p * gw[1 * C_ + c];
    float l2 = p * gw[2 * C_ + c], l3 = p * gw[3 * C_ + c];
    #pragma unroll
    for (int off = 32; off; off >>= 1) {
        l0 += __shfl_down(l0, off); l1 += __shfl_down(l1, off);
        l2 += __shfl_down(l2, off); l3 += __shfl_down(l3, off);
    }
    __shared__ float red[4][4];
    const int wid = c >> 6, lane = c & 63;
    if (lane == 0) { red[wid][0] = l0; red[wid][1] = l1; red[wid][2] = l2; red[wid][3] = l3; }
    __syncthreads();
    if (c < 4) {
        float logit = red[0][c] + red[1][c] + red[2][c] + red[3][c];
        float m = logit;
        m = fmaxf(m, __shfl_xor(m, 1)); m = fmaxf(m, __shfl_xor(m, 2));
        float ex = expf(logit - m);
        float ssum = ex; ssum += __shfl_xor(ssum, 1); ssum += __shfl_xor(ssum, 2);
        gates[b * 4 + c] = ex / ssum;
    }
}

// ---------------- kernel 3: combine expert weights (tap-major k) ----------------
__global__ __launch_bounds__(256) void combine_kernel(const float* __restrict__ We,
                                                      const float* __restrict__ gates,
                                                      ushort* __restrict__ Wc) {
    const int o = blockIdx.x, c = threadIdx.x;
    __shared__ float g[64];
    if (c < 64) g[c] = gates[c];
    __syncthreads();
    float w[4][9];
    #pragma unroll
    for (int e = 0; e < 4; ++e) {
        const float* p = We + (((size_t)e * O_ + o) * C_ + c) * 9;
        #pragma unroll
        for (int tap = 0; tap < 9; ++tap) w[e][tap] = p[tap];
    }
    #pragma unroll
    for (int b = 0; b < B_; ++b) {
        float g0 = g[b*4+0], g1 = g[b*4+1], g2 = g[b*4+2], g3 = g[b*4+3];
        #pragma unroll
        for (int tap = 0; tap < 9; ++tap) {
            float v = g0*w[0][tap] + g1*w[1][tap] + g2*w[2][tap] + g3*w[3][tap];
            Wc[((size_t)(b * O_ + o)) * KK_ + tap * C_ + c] = f2bf(v);
        }
    }
}

// ---------------- kernel 4: 256x256 conv GEMM — 2 barriers/tile (minimal-hazard) ----
// grid = 256 blocks = 1/CU, 512 threads (8 waves, 2M x 4N; wave 128x64). 36 K-tiles
// of BK=64, 2 dbuf (128KB), R7's 0-conflict 128B-row XOR swizzle.
// Only the two VMW(2)->BAR publish points remain (BAR2: B1(t) landed; BAR4:
// A0/A1/B0 of t+1 landed). BAR1/BAR3 of R19 proved hazard-free (pure phase-locks):
// A0/B0 reads covered by BAR4(t-1); B1 read covered by BAR2(t); every stage's
// target rows drained before BAR4(t-1) via each wave's own LGW(0)s. vm-FIFO stage
// order A0 | A1,B0,B1 and both VMW(2) counts unchanged (never 0 mid-loop).
__global__ __launch_bounds__(512, 2) void conv_kernel(const ushort* __restrict__ xT,
                                                      const ushort* __restrict__ Wc,
                                                      float* __restrict__ out) {
    __shared__ ushort As[2][256][64];   // [dbuf][o][k]  128B rows, linear DMA dest
    __shared__ ushort Bs[2][256][64];   // [dbuf][px][k]

    // bijective XCD chunk swizzle: 32 consecutive wgids per XCD (2 samples/XCD)
    const int d0 = blockIdx.x;
    const int wgid = (d0 & 7) * 32 + (d0 >> 3);
    const int b  = wgid >> 4;
    const int n0 = (wgid & 15) * 256;

    const int tid = threadIdx.x;
    const int wid = tid >> 6, lane = tid & 63;
    const int lr = lane & 15, lg = lane >> 4;
    const int wro = (wid >> 2) * 128;           // wave M-offset (o)
    const int wco = (wid & 3) * 64;             // wave N-offset (px)

    // staging lane roles (R7 swizzle: row = lane>>3, granule = (lane&7)^row)
    const int srow = lane >> 3;                 // 0..7
    const int sgr  = (lane & 7) ^ srow;
    const int rA = (wid >> 2) * 128 + (wid & 3) * 16;
    const ushort* aSb = Wc + ((size_t)(b * O_ + rA + srow)) * KK_ + sgr * 8;
    const ushort* xb = xT + (size_t)b * HP_ * HP_ * C_;
    const int hh  = (n0 >> 6) + (wid & 3);      // image row staged by this wave (uniform)
    const int pW  = (wid >> 2) * 16;            // px offset within row-half
    const ushort* bSb = xb + ((size_t)(hh + 1) * HP_ + pW + srow + 1) * C_ + sgr * 8;

    f32x4 acc[8][4];
    #pragma unroll
    for (int i = 0; i < 8; ++i)
        #pragma unroll
        for (int j = 0; j < 4; ++j) acc[i][j] = (f32x4){0.f, 0.f, 0.f, 0.f};

    auto stageA = [&](int dn, int t, int ah) {
        #pragma unroll
        for (int i = 0; i < 2; ++i)
            gl16(aSb + (size_t)(ah * 64 + i * 8) * KK_ + t * 64,
                 &As[dn][rA + ah * 64 + i * 8][0]);
    };
    auto stageB = [&](int dn, int t, int bh) {
        const int tap = t >> 2, c0 = (t & 3) * 64;
        const int t3 = (tap * 11) >> 5;          // tap/3
        const int toff = ((t3 - 1) * HP_ + (tap - 3 * t3 - 1)) * C_ + c0;
        #pragma unroll
        for (int i = 0; i < 2; ++i)
            gl16(bSb + (size_t)(bh * 32 + i * 8) * C_ + toff,
                 &Bs[dn][wco + pW + bh * 32 + i * 8][0]);
    };

    bf16x8 aF[4][2], bF0[2][2], bF1[2][2];

    auto rdA = [&](int dd, int mh, bf16x8 dst[4][2]) {
        #pragma unroll
        for (int m = 0; m < 4; ++m)
            #pragma unroll
            for (int k = 0; k < 2; ++k)
                dst[m][k] = *(const bf16x8*)
                    &As[dd][wro + mh * 64 + m * 16 + lr][(((k << 2) | lg) ^ (lr & 7)) * 8];
    };
    auto rdB = [&](int dd, int nh, bf16x8 dst[2][2]) {
        #pragma unroll
        for (int n = 0; n < 2; ++n)
            #pragma unroll
            for (int k = 0; k < 2; ++k)
                dst[n][k] = *(const bf16x8*)
                    &Bs[dd][wco + nh * 32 + n * 16 + lr][(((k << 2) | lg) ^ (lr & 7)) * 8];
    };
    auto mfmaQ = [&](int m0, int n0q, bf16x8 a[4][2], bf16x8 bv[2][2]) {
        #pragma unroll
        for (int m = 0; m < 4; ++m)
            #pragma unroll
            for (int n = 0; n < 2; ++n)
                #pragma unroll
                for (int k = 0; k < 2; ++k)
                    acc[m0 + m][n0q + n] =
                        __builtin_amdgcn_mfma_f32_16x16x32_bf16(a[m][k], bv[n][k], acc[m0 + m][n0q + n], 0, 0, 0);
    };

    // prologue: stage tile 0 fully into dbuf 0 (order A0,A1,B0,B1); VMW(2)+BAR
    stageA(0, 0, 0); stageA(0, 0, 1); stageB(0, 0, 0); stageB(0, 0, 1);
    VMW(2);                    // A0,A1,B0 landed; B1 (last pair) still in flight
    BAR;

    #pragma unroll 1
    for (int t = 0; t < 35; ++t) {
        const int dd = t & 1, dn = dd ^ 1;
        // first half: reads A(mh0)+B(nh0) (safe since BAR4(t-1)); stage A-half0(t+1)
        rdA(dd, 0, aF); rdB(dd, 0, bF0);
        stageA(dn, t + 1, 0);
        LGW(0); SB0;
        PRIO1; mfmaQ(0, 0, aF, bF0); PRIO0;
        VMW(2);                // prev tile's B1 landed; own A-half0(t+1) in flight
        BAR;                   // publish B1(t)
        // second half: rdB1 (safe now) + remaining stages + 3 MFMA groups
        rdB(dd, 1, bF1);
        stageA(dn, t + 1, 1);
        LGW(0); SB0;
        PRIO1; mfmaQ(0, 2, aF, bF1); PRIO0;
        rdA(dd, 1, aF);        // overwrites aF after its h0 use (program order, no WAR)
        stageB(dn, t + 1, 0);
        LGW(0); SB0;
        PRIO1; mfmaQ(4, 2, aF, bF1); PRIO0;
        stageB(dn, t + 1, 1);
        PRIO1; mfmaQ(4, 0, aF, bF0); PRIO0;
        VMW(2);                // A0',A1',B0' of t+1 landed; B1' in flight
        BAR;                   // publish A0/A1/B0 of t+1
    }
    // tile 35 (dbuf 1), no staging
    {
        rdA(1, 0, aF); rdB(1, 0, bF0);
        LGW(0); SB0;
        PRIO1; mfmaQ(0, 0, aF, bF0); PRIO0;
        VMW(0);                // drain tile-34's B1
        BAR;
        rdB(1, 1, bF1);
        LGW(0); SB0;
        PRIO1; mfmaQ(0, 2, aF, bF1); PRIO0;
        rdA(1, 1, aF);
        LGW(0); SB0;
        PRIO1; mfmaQ(4, 2, aF, bF1); PRIO0;
        PRIO1; mfmaQ(4, 0, aF, bF0); PRIO0;
    }

    // epilogue: C/D layout col=lane&15, row=(lane>>4)*4+j
    #pragma unroll
    for (int m = 0; m < 8; ++m)
        #pragma unroll
        for (int n = 0; n < 4; ++n)
            #pragma unroll
            for (int j = 0; j < 4; ++j) {
                int ro = wro + m * 16 + lg * 4 + j;
                int co = n0 + wco + n * 16 + lr;
                out[((size_t)(b * O_ + ro)) * HW_ + co] = acc[m][n][j];
            }
}

extern "C" void kernel_launch(void* const* d_in, const int* in_sizes, int n_in,
                              void* d_out, int out_size, void* d_ws, size_t ws_size,
                              hipStream_t stream) {
    const float* x  = (const float*)d_in[0];
    const float* We = (const float*)d_in[1];
    const float* gw = (const float*)d_in[2];
    float* out = (float*)d_out;

    // ws: part @0 (256KB), gates @262144, Wc @263168 (18.87MB -> 19137536),
    //     xT @19137536 (16*66*66*256*2B = 35.68MB) -> ~54.8MB total
    float*  part  = (float*)d_ws;
    float*  gates = (float*)((char*)d_ws + 262144);
    ushort* Wcomb = (ushort*)((char*)d_ws + 263168);
    ushort* xTp   = (ushort*)((char*)d_ws + 19137536);

    transpose_kernel<<<dim3(64, 16), 256, 0, stream>>>(x, xTp, part);
    gate_kernel<<<16, 256, 0, stream>>>(part, gw, gates);
    combine_kernel<<<O_, 256, 0, stream>>>(We, gates, Wcomb);
    conv_kernel<<<256, 512, 0, stream>>>(xTp, Wcomb, out);
}